// Round 8
// baseline (57.566 us; speedup 1.0000x reference)
//
#include <hip/hip_runtime.h>

// B=256, T=256, D=384, HD=64
typedef __attribute__((ext_vector_type(8))) short bf16x8;
typedef __attribute__((ext_vector_type(4))) float f32x4;

__device__ inline unsigned short f2bf(float f) {
    unsigned u = __float_as_uint(f);
    return (unsigned short)((u + 0x7fffu + ((u >> 16) & 1u)) >> 16);
}

__device__ inline void gload16(const void* g, void* l) {
    __builtin_amdgcn_global_load_lds(
        (const __attribute__((address_space(1))) unsigned*)g,
        (__attribute__((address_space(3))) unsigned*)l, 16, 0, 0);
}

// ---------------------------------------------------------------------------
// Kernel 0: W = [Wq;Wk;Wv] -> bf16, frag-major + pre-swizzled (R7-verified):
//   Wp[kc*6144 + (((g*192 + col) ^ g) << 3) + kl] = W[col][kc*32 + g*8 + kl]
// ---------------------------------------------------------------------------
__global__ void wconv(const float* __restrict__ Wq, const float* __restrict__ Wk,
                      const float* __restrict__ Wv, short* __restrict__ Wp) {
    int i = blockIdx.x * 256 + threadIdx.x;
    if (i >= 192 * 384) return;
    int col = i / 384;          // output column 0..191 (h)
    int k   = i - col * 384;    // 0..383
    const float* src = col < 64 ? (Wq + col * 384)
                     : col < 128 ? (Wk + (col - 64) * 384)
                                 : (Wv + (col - 128) * 384);
    int kc = k >> 5, g = (k >> 3) & 3, kl = k & 7;
    Wp[kc * 6144 + (((g * 192 + col) ^ g) << 3) + kl] = (short)f2bf(src[k]);
}

// ---------------------------------------------------------------------------
// Kernel 1: QKV projection, STRIP-FREE x reads.
// Block = 64 rows x 192 cols (full N), 1024 blocks x 256 thr (4 waves 2Mx2N,
// wave = 32x96). The block's x panel (64 FULL rows = 96 KB, one contiguous
// region) is staged to LDS as bf16 ONCE via fully-sequential float4 loads
// (consecutive threads = consecutive 16B -> perfect DRAM streaming), then the
// 12-step k-loop reads A-frags from LDS (zero further x traffic, no barriers
// needed on x). W streams per-step from pre-packed Wp via global_load_lds
// (L2-hot, 12KB/step, double-buffered, R7-verified layout).
// LDS: xs 64x392 shorts (49KB) + W dbuf 24KB = 73KB -> 2 blocks/CU.
// Epilogue repack overlays the W buffers (24KB exactly).
// ---------------------------------------------------------------------------
__global__ __launch_bounds__(256, 2) void qkv_proj(
    const float* __restrict__ x, const short* __restrict__ Wp,
    short* __restrict__ Qw, short* __restrict__ Kw, short* __restrict__ Vw) {
    __shared__ short xs[64 * 392];          // 50176 B; stride 392 (16B-aligned)
    __shared__ short wst[2 * 6144];         // 24576 B

    const int tid = threadIdx.x;
    const int wv = tid >> 6, lane = tid & 63;
    const int g = lane >> 4, c = lane & 15;
    const int wm = (wv >> 1) * 32, wn = (wv & 1) * 96;
    const size_t m0 = (size_t)blockIdx.x * 64;

#define STAGE_W(KC, BUF)                                                      \
    {                                                                         \
        _Pragma("unroll")                                                     \
        for (int i_ = 0; i_ < 3; ++i_) {                                      \
            int seg = wv * 3 + i_;                                            \
            gload16(Wp + (KC) * 6144 + seg * 512 + lane * 8,                  \
                    wst + (BUF) * 6144 + seg * 512);                          \
        }                                                                     \
    }

    f32x4 acc[2][6];
#pragma unroll
    for (int i = 0; i < 2; ++i)
#pragma unroll
        for (int j = 0; j < 6; ++j) acc[i][j] = (f32x4){0.f, 0.f, 0.f, 0.f};

    // ---- stage W step 0 (async) + x panel (sequential streaming) ----
    STAGE_W(0, 0)
    for (int batch = 0; batch < 3; ++batch) {
        float4 t[8];
#pragma unroll
        for (int i = 0; i < 8; ++i) {
            int u = tid + 256 * (batch * 8 + i);    // 0..6143
            int row = u / 96, c4 = u - row * 96;    // 96 float4-chunks per row
            t[i] = *(const float4*)(x + (m0 + row) * 384 + c4 * 4);
        }
#pragma unroll
        for (int i = 0; i < 8; ++i) {
            int u = tid + 256 * (batch * 8 + i);
            int row = u / 96, c4 = u - row * 96;
            uint2 p;
            p.x = (unsigned)f2bf(t[i].x) | ((unsigned)f2bf(t[i].y) << 16);
            p.y = (unsigned)f2bf(t[i].z) | ((unsigned)f2bf(t[i].w) << 16);
            *(uint2*)&xs[row * 392 + c4 * 4] = p;
        }
    }
    asm volatile("s_waitcnt vmcnt(0)" ::: "memory");
    __syncthreads();

    // ---- k-loop: 12 steps of BK=32, W dbuf, x resident ----
    for (int s = 0; s < 12; ++s) {
        if (s < 11) STAGE_W(s + 1, (s + 1) & 1)
        const short* wb = wst + (s & 1) * 6144;
        bf16x8 af[2], bfr[6];
#pragma unroll
        for (int mi = 0; mi < 2; ++mi)
            af[mi] = *(const bf16x8*)&xs[(wm + 16 * mi + c) * 392 + s * 32 + g * 8];
#pragma unroll
        for (int nj = 0; nj < 6; ++nj)
            bfr[nj] = *(const bf16x8*)&wb[((g * 192 + wn + 16 * nj + c) ^ g) << 3];
#pragma unroll
        for (int mi = 0; mi < 2; ++mi)
#pragma unroll
            for (int nj = 0; nj < 6; ++nj)
                acc[mi][nj] = __builtin_amdgcn_mfma_f32_16x16x32_bf16(
                    af[mi], bfr[nj], acc[mi][nj], 0, 0, 0);
        asm volatile("s_waitcnt vmcnt(0)" ::: "memory");
        __syncthreads();
    }

    // ---- epilogue: acc -> LDS repack (overlays W bufs) -> coalesced stores.
    // C/D layout (verified): col = c, row = 4g + r within each 16x16 tile.
    short* ep = wst;                        // 64*192 shorts = 24576 B
#pragma unroll
    for (int mi = 0; mi < 2; ++mi)
#pragma unroll
        for (int nj = 0; nj < 6; ++nj) {
            const int row = wm + 16 * mi + 4 * g;
#pragma unroll
            for (int r = 0; r < 4; ++r)
                ep[(row + r) * 192 + wn + 16 * nj + c] = (short)f2bf(acc[mi][nj][r]);
        }
    __syncthreads();
#pragma unroll
    for (int p = 0; p < 2; ++p) {
        int u = tid + 256 * p;              // 0..511: row = u>>3, c8 = u&7
        int row = u >> 3, c8 = u & 7;
        *(uint4*)(Qw + (m0 + row) * 64 + c8 * 8) = *(const uint4*)&ep[row * 192 + c8 * 8];
        *(uint4*)(Kw + (m0 + row) * 64 + c8 * 8) = *(const uint4*)&ep[row * 192 + 64 + c8 * 8];
        *(uint4*)(Vw + (m0 + row) * 64 + c8 * 8) = *(const uint4*)&ep[row * 192 + 128 + c8 * 8];
    }
#undef STAGE_W
}

// ---------------------------------------------------------------------------
// Kernel 2: causal attention (R2/R7-verified, verbatim). 256 blocks x 512 thr,
// LDS 79 KB -> 2 blocks/CU. K [256][72]; V transposed [64][264] XOR-swizzled;
// Q direct global->regs. Wave w: q-tiles 16w and 240-16w (9 kv-tiles each).
// ---------------------------------------------------------------------------
__global__ __launch_bounds__(512, 2) void attn_mfma(
    const short* __restrict__ Qw, const short* __restrict__ Kw,
    const short* __restrict__ Vw, float* __restrict__ out) {
    __shared__ short Ksh[256 * 72];
    __shared__ short Vt[64 * 264];
    __shared__ short Pb[8][640];
    const int tid = threadIdx.x;
    const int wv = tid >> 6, lane = tid & 63;
    const int g = lane >> 4, c = lane & 15;
    const int b = blockIdx.x;
    const short* Qg = Qw + b * 16384;
    const short* Kg = Kw + b * 16384;
    const short* Vg = Vw + b * 16384;

#pragma unroll
    for (int p = 0; p < 4; ++p) {
        int idx = tid + 512 * p;
        int r = idx >> 3, q8 = idx & 7;
        *(uint4*)&Ksh[r * 72 + q8 * 8] = *(const uint4*)(Kg + r * 64 + q8 * 8);
    }
#pragma unroll
    for (int p = 0; p < 4; ++p) {
        int idx = tid + 512 * p;
        int r = idx >> 3, q8 = idx & 7;
        uint4 v = *(const uint4*)(Vg + r * 64 + q8 * 8);
        unsigned vw[4] = {v.x, v.y, v.z, v.w};
        int swz = (q8 & 7) << 3;
#pragma unroll
        for (int w2 = 0; w2 < 4; ++w2) {
            int h0 = q8 * 8 + w2 * 2;
            Vt[((h0 + 0) * 264 + r) ^ swz] = (short)(vw[w2] & 0xffff);
            Vt[((h0 + 1) * 264 + r) ^ swz] = (short)(vw[w2] >> 16);
        }
    }
    __syncthreads();

    for (int half = 0; half < 2; ++half) {
        const int q0 = (half == 0) ? 16 * wv : 240 - 16 * wv;
        bf16x8 qf0 = *(const bf16x8*)(Qg + (q0 + c) * 64 + g * 8);
        bf16x8 qf1 = *(const bf16x8*)(Qg + (q0 + c) * 64 + 32 + g * 8);
        f32x4 o[4];
#pragma unroll
        for (int nj = 0; nj < 4; ++nj) o[nj] = (f32x4){0.f, 0.f, 0.f, 0.f};
        float m[4] = {-INFINITY, -INFINITY, -INFINITY, -INFINITY};
        float ls[4] = {0.f, 0.f, 0.f, 0.f};
        const int jmax = (q0 + 15) >> 5;

        for (int j = 0; j <= jmax; ++j) {
            f32x4 s0 = {0.f, 0.f, 0.f, 0.f}, s1 = {0.f, 0.f, 0.f, 0.f};
            {
                bf16x8 kf;
                kf = *(const bf16x8*)&Ksh[(32 * j + c) * 72 + g * 8];
                s0 = __builtin_amdgcn_mfma_f32_16x16x32_bf16(qf0, kf, s0, 0, 0, 0);
                kf = *(const bf16x8*)&Ksh[(32 * j + c) * 72 + 32 + g * 8];
                s0 = __builtin_amdgcn_mfma_f32_16x16x32_bf16(qf1, kf, s0, 0, 0, 0);
                kf = *(const bf16x8*)&Ksh[(32 * j + 16 + c) * 72 + g * 8];
                s1 = __builtin_amdgcn_mfma_f32_16x16x32_bf16(qf0, kf, s1, 0, 0, 0);
                kf = *(const bf16x8*)&Ksh[(32 * j + 16 + c) * 72 + 32 + g * 8];
                s1 = __builtin_amdgcn_mfma_f32_16x16x32_bf16(qf1, kf, s1, 0, 0, 0);
            }
            float t0[4], t1[4];
#pragma unroll
            for (int r = 0; r < 4; ++r) {
                t0[r] = s0[r] * 0.125f;
                t1[r] = s1[r] * 0.125f;
            }
            if (j == jmax) {   // wave-uniform: diagonal tile, causal mask
                int q = q0 + 4 * g;
#pragma unroll
                for (int r = 0; r < 4; ++r) {
                    if (32 * j + c > q + r) t0[r] = -INFINITY;
                    if (32 * j + 16 + c > q + r) t1[r] = -INFINITY;
                }
            }
            float corr[4], p0[4], p1[4];
#pragma unroll
            for (int r = 0; r < 4; ++r) {
                float v = fmaxf(t0[r], t1[r]);
#pragma unroll
                for (int off = 1; off < 16; off <<= 1) v = fmaxf(v, __shfl_xor(v, off, 16));
                float mn = fmaxf(m[r], v);
                corr[r] = __expf(m[r] - mn);   // first tile: exp(-inf)=0
                m[r] = mn;
                p0[r] = __expf(t0[r] - mn);
                p1[r] = __expf(t1[r] - mn);
                float rs = p0[r] + p1[r];
#pragma unroll
                for (int off = 1; off < 16; off <<= 1) rs += __shfl_xor(rs, off, 16);
                ls[r] = ls[r] * corr[r] + rs;
            }
#pragma unroll
            for (int nj = 0; nj < 4; ++nj) {
                f32x4 t = o[nj];
                t[0] *= corr[0]; t[1] *= corr[1]; t[2] *= corr[2]; t[3] *= corr[3];
                o[nj] = t;
            }
            short* pb = Pb[wv];
#pragma unroll
            for (int r = 0; r < 4; ++r) {
                pb[(4 * g + r) * 40 + c]      = (short)f2bf(p0[r]);
                pb[(4 * g + r) * 40 + 16 + c] = (short)f2bf(p1[r]);
            }
            bf16x8 pfa = *(const bf16x8*)&pb[c * 40 + g * 8];
#pragma unroll
            for (int nj = 0; nj < 4; ++nj) {
                int h = 16 * nj + c;
                int swz = ((2 * nj + (c >> 3)) & 7) << 3;
                bf16x8 vf = *(const bf16x8*)&Vt[(h * 264 + 32 * j + g * 8) ^ swz];
                o[nj] = __builtin_amdgcn_mfma_f32_16x16x32_bf16(pfa, vf, o[nj], 0, 0, 0);
            }
        }
        float inv[4];
#pragma unroll
        for (int r = 0; r < 4; ++r) inv[r] = 1.f / ls[r];
        float* ob = out + ((size_t)b * 256 + q0) * 64;
#pragma unroll
        for (int nj = 0; nj < 4; ++nj)
#pragma unroll
            for (int r = 0; r < 4; ++r)
                ob[(4 * g + r) * 64 + 16 * nj + c] = o[nj][r] * inv[r];
    }
}

// ---------------------------------------------------------------------------
extern "C" void kernel_launch(void* const* d_in, const int* in_sizes, int n_in,
                              void* d_out, int out_size, void* d_ws, size_t ws_size,
                              hipStream_t stream) {
    const float* x  = (const float*)d_in[0];
    const float* Wq = (const float*)d_in[1];
    const float* Wk = (const float*)d_in[2];
    const float* Wv = (const float*)d_in[3];
    float* out = (float*)d_out;

    // ws: Q | K | V (each 65536*64 bf16 = 8 MB) | Wp (73728 shorts)
    short* Qws = (short*)d_ws;
    short* Kws = Qws + (size_t)65536 * 64;
    short* Vws = Kws + (size_t)65536 * 64;
    short* Wp  = Vws + (size_t)65536 * 64;

    wconv<<<dim3(288), dim3(256), 0, stream>>>(Wq, Wk, Wv, Wp);
    qkv_proj<<<dim3(1024), dim3(256), 0, stream>>>(x, Wp, Qws, Kws, Vws);
    attn_mfma<<<dim3(256), dim3(512), 0, stream>>>(Qws, Kws, Vws, out);
}

// Round 9
// 42.749 us; speedup vs baseline: 1.3466x; 1.3466x over previous
//
#include <hip/hip_runtime.h>

// B=256, T=256, D=384, HD=64
typedef __attribute__((ext_vector_type(8))) short bf16x8;
typedef __attribute__((ext_vector_type(4))) float f32x4;

__device__ inline unsigned short f2bf(float f) {
    unsigned u = __float_as_uint(f);
    return (unsigned short)((u + 0x7fffu + ((u >> 16) & 1u)) >> 16);
}

__device__ inline void gload16(const void* g, void* l) {
    __builtin_amdgcn_global_load_lds(
        (const __attribute__((address_space(1))) unsigned*)g,
        (__attribute__((address_space(3))) unsigned*)l, 16, 0, 0);
}

// ---------------------------------------------------------------------------
// Kernel 0 (R7-verified): W = [Wq;Wk;Wv] -> bf16, frag-major + pre-swizzled:
//   Wp[kc*6144 + (((g*192 + col) ^ g) << 3) + kl] = W[col][kc*32 + g*8 + kl]
// so per-step staging is a linear 12 KB global_load_lds copy and B-frags are
// single b128 reads at ((g*192+col)^g)<<3.
// ---------------------------------------------------------------------------
__global__ void wconv(const float* __restrict__ Wq, const float* __restrict__ Wk,
                      const float* __restrict__ Wv, short* __restrict__ Wp) {
    int i = blockIdx.x * 256 + threadIdx.x;
    if (i >= 192 * 384) return;
    int col = i / 384;          // output column 0..191 (h)
    int k   = i - col * 384;    // 0..383
    const float* src = col < 64 ? (Wq + col * 384)
                     : col < 128 ? (Wk + (col - 64) * 384)
                                 : (Wv + (col - 128) * 384);
    int kc = k >> 5, g = (k >> 3) & 3, kl = k & 7;
    Wp[kc * 6144 + (((g * 192 + col) ^ g) << 3) + kl] = (short)f2bf(src[k]);
}

// ---------------------------------------------------------------------------
// Fused kernel v2: block = 1 batch, 16 waves (1024 thr) -> 4 waves/SIMD
// (R5-fused was 2/SIMD; its counters showed pure occupancy starvation).
// Phase 1: wave wv computes rows [16wv,16wv+16) x all 192 cols.
//   acc[12] f32x4 = 48 VGPR (fits the 1024-thread 128-reg cap).
//   x: per-step [256][32] f32 -> bf16 reg-staged into LDS (stride 40,
//      2-way-free), double-buffered, loads issued early / written late.
//   W: per-step 12 KB linear global_load_lds from pre-swizzled Wp, dbuf.
//   One vmcnt(0)+barrier per step (R7 pattern).
// LDS 89 KB total via overlays (regions dead until epilogue):
//   W dbuf (12288 sh) inside Ksh (18432 sh); x dbuf (20480 sh) inside
//   Vt+Pb (27136 sh). Epilogue (after final barrier): acc -> Ksh / Vt
//   (verified layouts); Q cols stay in REGISTERS via per-wave Pb C/D->A
//   round-trip (same pattern as P in the attn loop). One barrier -> phase 2.
// Phase 2: verified causal online-softmax MFMA attention, wave wv owns
//   q-tile [16wv,16wv+16) (single tile; critical path 8 kv-tiles).
// ---------------------------------------------------------------------------
__global__ __launch_bounds__(1024) void fused_attn(
    const float* __restrict__ x, const short* __restrict__ Wp,
    float* __restrict__ out) {
    __shared__ short LDSH[45568];          // 91136 B
    short* const Ksh = LDSH;               // [256*72]
    short* const Vt  = LDSH + 18432;       // [64*264]
    short* const Pb  = LDSH + 35328;       // [16*640]
    short* const wst = LDSH;               // W dbuf overlay: 2*6144
    short* const xst = LDSH + 18432;       // x dbuf overlay: 2*10240

    const int tid = threadIdx.x;
    const int wv = tid >> 6, lane = tid & 63;
    const int g = lane >> 4, c = lane & 15;
    const int b = blockIdx.x;
    const int q0 = wv * 16;

    // ---------------- Phase 1: QKV projection ----------------
    // x staging map: u = tid + 1024*i (i=0,1) -> row u>>3 (0..255), chunk u&7
    const int xr0 = tid >> 3;              // 0..127
    const int xc4 = tid & 7;
    const float* gx0 = x + ((size_t)b * 256 + xr0) * 384 + xc4 * 4;
    const float* gx1 = gx0 + (size_t)128 * 384;

    f32x4 acc[12];
#pragma unroll
    for (int j = 0; j < 12; ++j) acc[j] = (f32x4){0.f, 0.f, 0.f, 0.f};

#define STAGE_W(S, BUF)                                                       \
    if (wv < 12) gload16(Wp + (S) * 6144 + wv * 512 + lane * 8,               \
                         wst + (BUF) * 6144 + wv * 512);
#define XWRITE(BUF, A, Bv)                                                    \
    {                                                                         \
        uint2 p0_, p1_;                                                       \
        p0_.x = (unsigned)f2bf((A).x) | ((unsigned)f2bf((A).y) << 16);        \
        p0_.y = (unsigned)f2bf((A).z) | ((unsigned)f2bf((A).w) << 16);        \
        p1_.x = (unsigned)f2bf((Bv).x) | ((unsigned)f2bf((Bv).y) << 16);      \
        p1_.y = (unsigned)f2bf((Bv).z) | ((unsigned)f2bf((Bv).w) << 16);      \
        *(uint2*)&xst[(BUF) * 10240 + xr0 * 40 + xc4 * 4] = p0_;              \
        *(uint2*)&xst[(BUF) * 10240 + (xr0 + 128) * 40 + xc4 * 4] = p1_;      \
    }

    // prologue: stage step 0
    STAGE_W(0, 0)
    {
        float4 a0 = *(const float4*)(gx0);
        float4 a1 = *(const float4*)(gx1);
        XWRITE(0, a0, a1)
    }
    asm volatile("s_waitcnt vmcnt(0)" ::: "memory");
    __syncthreads();

    for (int s = 0; s < 12; ++s) {
        float4 na0, na1;
        if (s < 11) {                       // issue next-step loads EARLY
            na0 = *(const float4*)(gx0 + (s + 1) * 32);
            na1 = *(const float4*)(gx1 + (s + 1) * 32);
            STAGE_W(s + 1, (s + 1) & 1)     // async into the dead buffer
        }
        const short* xb = xst + (s & 1) * 10240;
        const short* wb = wst + (s & 1) * 6144;
        bf16x8 af = *(const bf16x8*)&xb[(q0 + c) * 40 + g * 8];
#pragma unroll
        for (int h_ = 0; h_ < 2; ++h_) {
            bf16x8 bfr[6];
#pragma unroll
            for (int j6 = 0; j6 < 6; ++j6) {
                int col = (h_ * 6 + j6) * 16 + c;
                bfr[j6] = *(const bf16x8*)&wb[((g * 192 + col) ^ g) << 3];
            }
#pragma unroll
            for (int j6 = 0; j6 < 6; ++j6)
                acc[h_ * 6 + j6] = __builtin_amdgcn_mfma_f32_16x16x32_bf16(
                    af, bfr[j6], acc[h_ * 6 + j6], 0, 0, 0);
        }
        if (s < 11) XWRITE((s + 1) & 1, na0, na1)   // write-late (dead buffer)
        asm volatile("s_waitcnt vmcnt(0)" ::: "memory");
        __syncthreads();
    }

    // ---- epilogue: acc -> K/V LDS + Q -> registers via per-wave Pb ----
    // C/D layout (verified): within 16x16 tile, col = c, row = 4g + r.
    short* const pbw = Pb + wv * 640;
    bf16x8 qf0, qf1;
    {
#pragma unroll
        for (int r = 0; r < 4; ++r) {
            pbw[(4 * g + r) * 40 + c]      = (short)f2bf(acc[0][r]);
            pbw[(4 * g + r) * 40 + 16 + c] = (short)f2bf(acc[1][r]);
        }
        qf0 = *(const bf16x8*)&pbw[c * 40 + g * 8];
#pragma unroll
        for (int r = 0; r < 4; ++r) {
            pbw[(4 * g + r) * 40 + c]      = (short)f2bf(acc[2][r]);
            pbw[(4 * g + r) * 40 + 16 + c] = (short)f2bf(acc[3][r]);
        }
        qf1 = *(const bf16x8*)&pbw[c * 40 + g * 8];
    }
#pragma unroll
    for (int nj = 4; nj < 8; ++nj) {
        const int row = q0 + 4 * g;
#pragma unroll
        for (int r = 0; r < 4; ++r)
            Ksh[(row + r) * 72 + (nj - 4) * 16 + c] = (short)f2bf(acc[nj][r]);
    }
#pragma unroll
    for (int nj = 8; nj < 12; ++nj) {
        const int h = (nj - 8) * 16 + c;
        const int swz = ((h >> 3) & 7) << 3;
        const int row = q0 + 4 * g;
#pragma unroll
        for (int r = 0; r < 4; ++r)
            Vt[(h * 264 + row + r) ^ swz] = (short)f2bf(acc[nj][r]);
    }
    __syncthreads();

    // ---------------- Phase 2: causal attention (verified) ----------------
    {
        f32x4 o[4];
#pragma unroll
        for (int nj = 0; nj < 4; ++nj) o[nj] = (f32x4){0.f, 0.f, 0.f, 0.f};
        float m[4] = {-INFINITY, -INFINITY, -INFINITY, -INFINITY};
        float ls[4] = {0.f, 0.f, 0.f, 0.f};
        const int jmax = (q0 + 15) >> 5;

        for (int j = 0; j <= jmax; ++j) {
            f32x4 s0 = {0.f, 0.f, 0.f, 0.f}, s1 = {0.f, 0.f, 0.f, 0.f};
            {
                bf16x8 kf;
                kf = *(const bf16x8*)&Ksh[(32 * j + c) * 72 + g * 8];
                s0 = __builtin_amdgcn_mfma_f32_16x16x32_bf16(qf0, kf, s0, 0, 0, 0);
                kf = *(const bf16x8*)&Ksh[(32 * j + c) * 72 + 32 + g * 8];
                s0 = __builtin_amdgcn_mfma_f32_16x16x32_bf16(qf1, kf, s0, 0, 0, 0);
                kf = *(const bf16x8*)&Ksh[(32 * j + 16 + c) * 72 + g * 8];
                s1 = __builtin_amdgcn_mfma_f32_16x16x32_bf16(qf0, kf, s1, 0, 0, 0);
                kf = *(const bf16x8*)&Ksh[(32 * j + 16 + c) * 72 + 32 + g * 8];
                s1 = __builtin_amdgcn_mfma_f32_16x16x32_bf16(qf1, kf, s1, 0, 0, 0);
            }
            float t0[4], t1[4];
#pragma unroll
            for (int r = 0; r < 4; ++r) {
                t0[r] = s0[r] * 0.125f;
                t1[r] = s1[r] * 0.125f;
            }
            if (j == jmax) {   // wave-uniform: diagonal tile, causal mask
                int q = q0 + 4 * g;
#pragma unroll
                for (int r = 0; r < 4; ++r) {
                    if (32 * j + c > q + r) t0[r] = -INFINITY;
                    if (32 * j + 16 + c > q + r) t1[r] = -INFINITY;
                }
            }
            float corr[4], p0[4], p1[4];
#pragma unroll
            for (int r = 0; r < 4; ++r) {
                float v = fmaxf(t0[r], t1[r]);
#pragma unroll
                for (int off = 1; off < 16; off <<= 1) v = fmaxf(v, __shfl_xor(v, off, 16));
                float mn = fmaxf(m[r], v);
                corr[r] = __expf(m[r] - mn);   // first tile: exp(-inf)=0
                m[r] = mn;
                p0[r] = __expf(t0[r] - mn);
                p1[r] = __expf(t1[r] - mn);
                float rs = p0[r] + p1[r];
#pragma unroll
                for (int off = 1; off < 16; off <<= 1) rs += __shfl_xor(rs, off, 16);
                ls[r] = ls[r] * corr[r] + rs;
            }
#pragma unroll
            for (int nj = 0; nj < 4; ++nj) {
                f32x4 t = o[nj];
                t[0] *= corr[0]; t[1] *= corr[1]; t[2] *= corr[2]; t[3] *= corr[3];
                o[nj] = t;
            }
            // P -> Pb (C/D rows) -> A-frag read (same-wave RAW, in-order LDS)
#pragma unroll
            for (int r = 0; r < 4; ++r) {
                pbw[(4 * g + r) * 40 + c]      = (short)f2bf(p0[r]);
                pbw[(4 * g + r) * 40 + 16 + c] = (short)f2bf(p1[r]);
            }
            bf16x8 pfa = *(const bf16x8*)&pbw[c * 40 + g * 8];
#pragma unroll
            for (int nj = 0; nj < 4; ++nj) {
                int h = 16 * nj + c;
                int swz = ((2 * nj + (c >> 3)) & 7) << 3;
                bf16x8 vf = *(const bf16x8*)&Vt[(h * 264 + 32 * j + g * 8) ^ swz];
                o[nj] = __builtin_amdgcn_mfma_f32_16x16x32_bf16(pfa, vf, o[nj], 0, 0, 0);
            }
        }
        float inv[4];
#pragma unroll
        for (int r = 0; r < 4; ++r) inv[r] = 1.f / ls[r];
        float* ob = out + ((size_t)b * 256 + q0) * 64;
#pragma unroll
        for (int nj = 0; nj < 4; ++nj)
#pragma unroll
            for (int r = 0; r < 4; ++r)
                ob[(4 * g + r) * 64 + 16 * nj + c] = o[nj][r] * inv[r];
    }
#undef STAGE_W
#undef XWRITE
}

// ---------------------------------------------------------------------------
extern "C" void kernel_launch(void* const* d_in, const int* in_sizes, int n_in,
                              void* d_out, int out_size, void* d_ws, size_t ws_size,
                              hipStream_t stream) {
    const float* x  = (const float*)d_in[0];
    const float* Wq = (const float*)d_in[1];
    const float* Wk = (const float*)d_in[2];
    const float* Wv = (const float*)d_in[3];
    float* out = (float*)d_out;

    short* Wp = (short*)d_ws;   // 73728 shorts (144 KB)

    wconv<<<dim3(288), dim3(256), 0, stream>>>(Wq, Wk, Wv, Wp);
    fused_attn<<<dim3(256), dim3(1024), 0, stream>>>(x, Wp, out);
}